// Round 15
// baseline (216.157 us; speedup 1.0000x reference)
//
#include <hip/hip_runtime.h>
#include <hip/hip_bf16.h>

// QLinear: per-row absmax int8 quant -> int8 GEMM (MFMA) -> fused dequant.
// M=8192, K=4096, N=4096 (derived from in_sizes at launch).

using int32x4 = __attribute__((ext_vector_type(4))) int;

#define QMAXF 127.0f

// ---------------------------------------------------------------------------
// Kernel 0: weight repack (int32-marshalled int8 -> packed int8).
// ---------------------------------------------------------------------------
__global__ __launch_bounds__(256) void repack_weights(
    const int* __restrict__ w, signed char* __restrict__ w8, int total)
{
    bool is32 = true;
#pragma unroll
    for (int i = 0; i < 16; ++i) {
        int v = w[i];
        is32 = is32 && (v >= -127 && v <= 127);
    }

    const int t = blockIdx.x * blockDim.x + threadIdx.x;
    const int nth = gridDim.x * blockDim.x;
    const int chunks = total / 16;

    if (is32) {
        for (int c = t; c < chunks; c += nth) {
            const int32x4* src = reinterpret_cast<const int32x4*>(w + (size_t)c * 16);
            int32x4 a0 = src[0], a1 = src[1], a2 = src[2], a3 = src[3];
            int32x4 o;
            o[0] = (a0[0] & 0xff) | ((a0[1] & 0xff) << 8) | ((a0[2] & 0xff) << 16) | ((a0[3] & 0xff) << 24);
            o[1] = (a1[0] & 0xff) | ((a1[1] & 0xff) << 8) | ((a1[2] & 0xff) << 16) | ((a1[3] & 0xff) << 24);
            o[2] = (a2[0] & 0xff) | ((a2[1] & 0xff) << 8) | ((a2[2] & 0xff) << 16) | ((a2[3] & 0xff) << 24);
            o[3] = (a3[0] & 0xff) | ((a3[1] & 0xff) << 8) | ((a3[2] & 0xff) << 16) | ((a3[3] & 0xff) << 24);
            reinterpret_cast<int32x4*>(w8)[c] = o;
        }
    } else {
        const int32x4* src = reinterpret_cast<const int32x4*>(w);
        int32x4* dst = reinterpret_cast<int32x4*>(w8);
        for (int c = t; c < chunks; c += nth) dst[c] = src[c];
    }
}

// ---------------------------------------------------------------------------
// Kernel 1: per-row absmax quantization. One block (256 thr) per row, K=4096.
// ---------------------------------------------------------------------------
__global__ __launch_bounds__(256) void quant_rows(
    const float* __restrict__ x, signed char* __restrict__ q,
    float* __restrict__ scale, int K)
{
    const int row = blockIdx.x;
    const int t = threadIdx.x;
    const float4* xr = reinterpret_cast<const float4*>(x + (size_t)row * K);

    float4 v[4];
    float m = 0.f;
#pragma unroll
    for (int i = 0; i < 4; ++i) {
        v[i] = xr[t + i * 256];
        m = fmaxf(m, fmaxf(fmaxf(fabsf(v[i].x), fabsf(v[i].y)),
                           fmaxf(fabsf(v[i].z), fabsf(v[i].w))));
    }
#pragma unroll
    for (int off = 32; off >= 1; off >>= 1)
        m = fmaxf(m, __shfl_xor(m, off, 64));
    __shared__ float wmax[4];
    const int wave = t >> 6;
    if ((t & 63) == 0) wmax[wave] = m;
    __syncthreads();
    m = fmaxf(fmaxf(wmax[0], wmax[1]), fmaxf(wmax[2], wmax[3]));

    const float s   = m / QMAXF;
    const float inv = (m > 0.f) ? (QMAXF / m) : 0.f;
    if (t == 0) scale[row] = s;

    int* qr = reinterpret_cast<int*>(q + (size_t)row * K);
#pragma unroll
    for (int i = 0; i < 4; ++i) {
        const float* f = reinterpret_cast<const float*>(&v[i]);
        unsigned int packed = 0;
#pragma unroll
        for (int j = 0; j < 4; ++j) {
            int qi = __float2int_rn(f[j] * inv);
            qi = qi > 127 ? 127 : (qi < -127 ? -127 : qi);
            packed |= ((unsigned int)(qi & 0xff)) << (8 * j);
        }
        qr[t + i * 256] = (int)packed;
    }
}

// ---------------------------------------------------------------------------
// Kernel 2: int8 GEMM, 256x256 tile, 16 waves (4Mx4N, 1024 thr, 4 waves/SIMD)
// x FINE-PHASE interleave (m201 geometry) -- the last untested cell of
// {schedule x occupancy}. r7 tested fine-phase at 2 waves/SIMD (null); r14
// tested 4 waves/SIMD with the coarse loop (+3%). Per the regime-gate lesson
// (levers interact non-additively), this probes the interaction: with 4
// waves/SIMD per phase the CU scheduler has both role diversity (waves in
// ds_read vs MFMA) and fine phases to arbitrate (setprio now meaningful).
//
// Geometry: BKB = 128 B (NT=32, halves barrier segments), NBUF=2 x 64 KiB
// (A 32KB + B 32KB per buffer) = 128 KiB. Per wave per iter: 4 stage loads
// (A frags {wave,16+wave}, B same), 16 ds_read_b128, 32 MFMA in 2 phases:
//   ph0: 8 ds_reads (ksl=0) || 4 stage loads of t+1 -> BAR -> LGKM0 ->
//        setprio1 16 MFMA setprio0 -> BAR
//   ph1: 8 ds_reads (ksl=1)                        -> LGKM0 ->
//        setprio1 16 MFMA setprio0 -> VM0 -> BAR
// Hazard ledger (NBUF=2): iter t reads buf t&1 (drained by ph1 LGKM0 before
// iter-end BAR); stage of t+1 writes buf (t+1)&1 = buf of iter t-1, whose
// readers drained before iter t-1's final BAR (fenced barriers pin order);
// VM0 at iter end (cover: ph0 MFMA + ph1 reads + ph1 MFMA ~ 700+ cyc)
// + BAR makes t+1's DMA visible to all waves. Every barrier two-side
// fenced (sched_barrier + asm memory clobber) -- round-6 race fix.
//
// Fragment-order LDS (zero bank conflicts): frag fi = rg*2+sl (rg 0..15,
// sl 0..1) = 16 rows x 64 k-bytes, lane-linear at fi*1024 + lane*16;
// per-lane global src row rg*16+(l&15), col kt + sl*64 + (l>>4)*16.
// ---------------------------------------------------------------------------
#define BM 256
#define BN 256
#define BKB 128
#define NBUF 2
#define BUFSZ 65536

__device__ __forceinline__ void async_copy16(const void* g, void* lds) {
    __builtin_amdgcn_global_load_lds(
        (const __attribute__((address_space(1))) void*)g,
        (__attribute__((address_space(3))) void*)lds, 16, 0, 0);
}

#define BARF do {                                         \
    __builtin_amdgcn_sched_barrier(0);                    \
    asm volatile("" ::: "memory");                        \
    __builtin_amdgcn_s_barrier();                         \
    asm volatile("" ::: "memory");                        \
    __builtin_amdgcn_sched_barrier(0);                    \
} while (0)

#define LGKM0 asm volatile("s_waitcnt lgkmcnt(0)" ::: "memory")
#define VM0   asm volatile("s_waitcnt vmcnt(0)" ::: "memory")

__global__ __launch_bounds__(1024) void gemm_i8_dequant_ph16(
    const signed char* __restrict__ A,   // [M,K] qinp
    const signed char* __restrict__ B,   // [N,K] qweight (packed int8)
    const float* __restrict__ a_scale,   // [M]
    const float* __restrict__ wparams,   // [N]
    const float* __restrict__ bias,      // [N]
    float* __restrict__ out,             // [M,N]
    int M, int N, int K)
{
    __shared__ __align__(16) signed char lds[NBUF * BUFSZ];   // 128 KiB

    const int t    = threadIdx.x;
    const int lane = t & 63;
    const int wave = t >> 6;           // 0..15
    const int wr   = wave >> 2;        // 0..3 (M quarter: 64 rows)
    const int wc   = wave & 3;         // 0..3 (N quarter: 64 cols)

    // T1: XCD-aware bijective swizzle (nwg % 8 == 0)
    const int nwg = gridDim.x;
    const int cpx = nwg >> 3;
    const int swz = (blockIdx.x & 7) * cpx + (blockIdx.x >> 3);
    const int nbx = N / BN;
    const int rowBase = (swz / nbx) * BM;
    const int colBase = (swz % nbx) * BN;

    const int r15 = lane & 15;
    const int ksl = lane >> 4;

    int32x4 acc[4][4] = {};
    const int NT = K / BKB;            // 32

    // staging: wave stages frag fi=wave (rg=wave>>1, sl=wave&1) and
    // fi=16+wave (rg=8+(wave>>1), same sl) for both A and B.
    const int rg0 = wave >> 1, sl0 = wave & 1;
    const signed char* gA0 = A + (size_t)(rowBase + rg0 * 16 + r15) * K
                               + sl0 * 64 + ksl * 16;
    const signed char* gA1 = A + (size_t)(rowBase + (8 + rg0) * 16 + r15) * K
                               + sl0 * 64 + ksl * 16;
    const signed char* gB0 = B + (size_t)(colBase + rg0 * 16 + r15) * K
                               + sl0 * 64 + ksl * 16;
    const signed char* gB1 = B + (size_t)(colBase + (8 + rg0) * 16 + r15) * K
                               + sl0 * 64 + ksl * 16;
    const int fi0 = wave, fi1 = 16 + wave;

    auto stage = [&](int tile) {
        signed char* L = lds + (tile & 1) * BUFSZ;
        const size_t kt = (size_t)tile * BKB;
        async_copy16(gA0 + kt, L + fi0 * 1024);
        async_copy16(gA1 + kt, L + fi1 * 1024);
        async_copy16(gB0 + kt, L + 32768 + fi0 * 1024);
        async_copy16(gB1 + kt, L + 32768 + fi1 * 1024);
    };

    auto ldFragsSl = [&](int tile, int sl, int32x4 (&fa)[4], int32x4 (&fb)[4]) {
        const signed char* base = lds + (tile & 1) * BUFSZ + lane * 16;
#pragma unroll
        for (int mm = 0; mm < 4; ++mm)
            fa[mm] = *reinterpret_cast<const int32x4*>(
                base + ((wr * 4 + mm) * 2 + sl) * 1024);
#pragma unroll
        for (int nn = 0; nn < 4; ++nn)
            fb[nn] = *reinterpret_cast<const int32x4*>(
                base + 32768 + ((wc * 4 + nn) * 2 + sl) * 1024);
    };

    auto mfma16 = [&](const int32x4 (&fa)[4], const int32x4 (&fb)[4]) {
        __builtin_amdgcn_s_setprio(1);
#pragma unroll
        for (int mm = 0; mm < 4; ++mm)
#pragma unroll
            for (int nn = 0; nn < 4; ++nn)
                acc[mm][nn] = __builtin_amdgcn_mfma_i32_16x16x64_i8(
                    fa[mm], fb[nn], acc[mm][nn], 0, 0, 0);
        __builtin_amdgcn_s_setprio(0);
    };

    int32x4 af[4], bf[4];

    // ---- prologue: stage tile 0 ----
    stage(0);
    VM0;
    BARF;

    // ---- iters 0 .. NT-2 (with stage of t+1) ----
    for (int tt = 0; tt < NT - 1; ++tt) {
        // phase 0: reads ksl0 || stage t+1
        ldFragsSl(tt, 0, af, bf);
        stage(tt + 1);
        BARF; LGKM0;
        mfma16(af, bf);
        BARF;
        // phase 1: reads ksl1
        ldFragsSl(tt, 1, af, bf);
        LGKM0;
        mfma16(af, bf);
        VM0;                           // t+1's DMA landed (~700+ cyc cover)
        BARF;
    }
    // ---- tail: tile NT-1, no stage ----
    ldFragsSl(NT - 1, 0, af, bf);
    LGKM0;
    mfma16(af, bf);
    ldFragsSl(NT - 1, 1, af, bf);
    LGKM0;
    mfma16(af, bf);

    // ---- epilogue: dequant + bias. C/D map: col=lane&15, row=(lane>>4)*4+r
#pragma unroll
    for (int mm = 0; mm < 4; ++mm) {
        const int rb = rowBase + wr * 64 + mm * 16 + ksl * 4;
        float asc[4];
#pragma unroll
        for (int r = 0; r < 4; ++r) asc[r] = a_scale[rb + r];
#pragma unroll
        for (int nn = 0; nn < 4; ++nn) {
            const int col = colBase + wc * 64 + nn * 16 + r15;
            const float wp = wparams[col];
            const float bs = bias[col];
#pragma unroll
            for (int r = 0; r < 4; ++r) {
                out[(size_t)(rb + r) * N + col] =
                    (float)acc[mm][nn][r] * asc[r] * wp + bs;
            }
        }
    }
}

// ---------------------------------------------------------------------------
extern "C" void kernel_launch(void* const* d_in, const int* in_sizes, int n_in,
                              void* d_out, int out_size, void* d_ws, size_t ws_size,
                              hipStream_t stream) {
    const float* inp     = (const float*)d_in[0];
    const int*   qw_raw  = (const int*)d_in[1];
    const float* wparams = (const float*)d_in[2];
    const float* bias    = (const float*)d_in[3];
    float*       out     = (float*)d_out;

    const int N = in_sizes[2];             // 4096
    const int K = in_sizes[1] / N;         // 4096
    const int M = in_sizes[0] / K;         // 8192

    // workspace: qinp [M*K B] | a_scale [M*4 B, 256-pad] | w8 [N*K B]
    signed char* qinp    = (signed char*)d_ws;
    float*       a_scale = (float*)((char*)d_ws + (size_t)M * K);
    size_t off_w8 = (size_t)M * K + (((size_t)M * sizeof(float) + 255) & ~(size_t)255);
    signed char* w8      = (signed char*)((char*)d_ws + off_w8);

    repack_weights<<<2048, 256, 0, stream>>>(qw_raw, w8, N * K);
    quant_rows<<<M, 256, 0, stream>>>(inp, qinp, a_scale, K);

    const int nwg = (M / BM) * (N / BN);   // 32*16 = 512, %8 == 0
    gemm_i8_dequant_ph16<<<nwg, 1024, 0, stream>>>(
        qinp, w8, a_scale, wparams, bias, out, M, N, K);
}